// Round 1
// baseline (709.421 us; speedup 1.0000x reference)
//
#include <hip/hip_runtime.h>
#include <hip/hip_bf16.h>
#include <cmath>

#define NB 8
#define NC 256
#define NHH 4
#define DD 64
#define LL 4096
#define NQ 64
#define NKB 64
#define BLK 64
#define TT 6

// ---------------- xb: per-block channel means of x ----------------
// grid: NB*NC blocks, 64 threads. xb[b][c][n] = mean_j x[b][c][n*64+j]
__global__ void xb_kernel(const float* __restrict__ x, float* __restrict__ xb) {
  int bc = blockIdx.x;
  const float* row = x + (size_t)bc * LL;
  int j = threadIdx.x;
  for (int n = 0; n < NQ; ++n) {
    float v = row[n * BLK + j];
#pragma unroll
    for (int off = 32; off > 0; off >>= 1) v += __shfl_xor(v, off);
    if (j == 0) xb[(size_t)bc * NQ + n] = v * (1.0f / 64.0f);
  }
}

// ---------------- qb/kb: project block means ----------------
// grid: NB*NQ*NHH blocks, 128 threads (t<64: q, t>=64: k)
__global__ void qbkb_kernel(const float* __restrict__ w, const float* __restrict__ xb,
                            float* __restrict__ qb, float* __restrict__ kb) {
  int id = blockIdx.x;
  int h = id % NHH; id /= NHH;
  int n = id % NQ;  int b = id / NQ;
  int t = threadIdx.x;
  int d = t & 63;
  int part = t >> 6;
  const float* wrow = w + (size_t)(part * NC + h * DD + d) * NC;
  const float* xcol = xb + (size_t)b * NC * NQ + n;
  float acc = 0.f;
#pragma unroll 4
  for (int c = 0; c < NC; ++c) acc += wrow[c] * xcol[(size_t)c * NQ];
  float* dst = (part == 0) ? qb : kb;
  dst[(((size_t)b * NHH + h) * NQ + n) * DD + d] = acc;
}

// ---------------- topk: block scores + iterative argmax ----------------
// grid: NB*NHH*NQ blocks ((bh)*NQ+n), 64 threads (one per key block m)
__global__ void topk_kernel(const float* __restrict__ qb, const float* __restrict__ kb,
                            int* __restrict__ lut) {
  __shared__ float kbs[NKB][DD + 1];
  int id = blockIdx.x;
  int n = id % NQ;
  int bh = id / NQ;
  int m = threadIdx.x;
  const float* kbp = kb + (size_t)bh * NKB * DD;
  for (int i = threadIdx.x; i < NKB * DD; i += 64) kbs[i >> 6][i & 63] = kbp[i];
  __syncthreads();
  const float* qrow = qb + ((size_t)bh * NQ + n) * DD;
  float s = 0.f;
#pragma unroll 8
  for (int d2 = 0; d2 < DD; ++d2) s += qrow[d2] * kbs[m][d2];
  for (int t = 0; t < TT; ++t) {
    float v = s; int i = m;
#pragma unroll
    for (int off = 1; off < 64; off <<= 1) {
      float ov = __shfl_xor(v, off);
      int oi = __shfl_xor(i, off);
      if (ov > v || (ov == v && oi < i)) { v = ov; i = oi; }
    }
    if (m == 0) lut[(size_t)id * TT + t] = i;
    if (m == i) s = -INFINITY;
  }
}

// ---------------- qkv GEMM: q,k,v in (B,H,L,D) f32 ----------------
// grid: (LL/64, 12, NB), 256 threads, 64(l)x64(o) tile, K=256 in 32-chunks
__global__ __launch_bounds__(256) void qkv_gemm(const float* __restrict__ x,
                                                const float* __restrict__ w,
                                                float* __restrict__ q,
                                                float* __restrict__ k,
                                                float* __restrict__ v) {
  __shared__ float Xs[32][BLK + 4];  // [cc][l]
  __shared__ float Wt[32][BLK + 4];  // [cc][o]
  int l0 = blockIdx.x * 64;
  int o0 = blockIdx.y * 64;
  int b = blockIdx.z;
  int tid = threadIdx.x;
  int tx = tid & 15, ty = tid >> 4;
  float acc[4][4] = {};
  const float* xp = x + (size_t)b * NC * LL + l0;
  const float* wp = w + (size_t)o0 * NC;
  int llA = tid & 63, ccA = tid >> 6;
  int j2B = tid & 31, rB = tid >> 5;
  for (int c0 = 0; c0 < NC; c0 += 32) {
#pragma unroll
    for (int s = 0; s < 8; ++s)
      Xs[ccA + s * 4][llA] = xp[(size_t)(c0 + ccA + s * 4) * LL + llA];
#pragma unroll
    for (int s = 0; s < 8; ++s)
      Wt[j2B][rB + s * 8] = wp[(size_t)(rB + s * 8) * NC + c0 + j2B];
    __syncthreads();
#pragma unroll
    for (int cc = 0; cc < 32; ++cc) {
      float a[4], bb[4];
#pragma unroll
      for (int i = 0; i < 4; ++i) a[i] = Xs[cc][ty * 4 + i];
#pragma unroll
      for (int j = 0; j < 4; ++j) bb[j] = Wt[cc][tx * 4 + j];
#pragma unroll
      for (int i = 0; i < 4; ++i)
#pragma unroll
        for (int j = 0; j < 4; ++j) acc[i][j] += a[i] * bb[j];
    }
    __syncthreads();
  }
  int part = o0 >> 8;
  int h = (o0 >> 6) & 3;
  float* dstbase = (part == 0) ? q : (part == 1 ? k : v);
  float* dst = dstbase + (((size_t)b * NHH + h) * LL + l0) * DD;
#pragma unroll
  for (int i = 0; i < 4; ++i) {
    float4 val = make_float4(acc[i][0], acc[i][1], acc[i][2], acc[i][3]);
    *reinterpret_cast<float4*>(&dst[(size_t)(ty * 4 + i) * DD + tx * 4]) = val;
  }
}

// ---------------- kvb + ksum per key block ----------------
// grid: NB*NHH*NKB ((bh)*NKB+m), 256 threads
__global__ __launch_bounds__(256) void kvb_kernel(const float* __restrict__ k,
                                                  const float* __restrict__ v,
                                                  float* __restrict__ kvb,
                                                  float* __restrict__ ksum) {
  __shared__ float ck[BLK][DD + 1];  // c_k rows [j][d]
  __shared__ float vs[BLK][DD + 4];  // v rows  [j][e]
  int id = blockIdx.x;
  int m = id % NKB;
  int bh = id / NKB;
  int tid = threadIdx.x;
  const float* kp = k + ((size_t)bh * LL + (size_t)m * BLK) * DD;
  const float* vp = v + ((size_t)bh * LL + (size_t)m * BLK) * DD;
  for (int i = tid; i < BLK * DD; i += 256) {
    ck[i >> 6][i & 63] = kp[i];
    vs[i >> 6][i & 63] = vp[i];
  }
  __syncthreads();
  {  // softmax over d per row; 4 threads per row
    int r = tid >> 2, p = tid & 3;
    float mx = -INFINITY;
#pragma unroll
    for (int c = 0; c < 16; ++c) mx = fmaxf(mx, ck[r][p * 16 + c]);
    mx = fmaxf(mx, __shfl_xor(mx, 1));
    mx = fmaxf(mx, __shfl_xor(mx, 2));
    float e[16]; float sum = 0.f;
#pragma unroll
    for (int c = 0; c < 16; ++c) { e[c] = __expf(ck[r][p * 16 + c] - mx); sum += e[c]; }
    sum += __shfl_xor(sum, 1);
    sum += __shfl_xor(sum, 2);
    float inv = 1.0f / sum;
#pragma unroll
    for (int c = 0; c < 16; ++c) ck[r][p * 16 + c] = e[c] * inv;
  }
  __syncthreads();
  if (tid < DD) {
    float s = 0.f;
#pragma unroll 8
    for (int j = 0; j < BLK; ++j) s += ck[j][tid];
    ksum[((size_t)bh * NKB + m) * DD + tid] = s;
  }
  int tx = tid & 15, ty = tid >> 4;
  float acc[4][4] = {};
#pragma unroll 4
  for (int j = 0; j < BLK; ++j) {
    float a[4], bb[4];
#pragma unroll
    for (int i = 0; i < 4; ++i) a[i] = ck[j][ty * 4 + i];
#pragma unroll
    for (int jj = 0; jj < 4; ++jj) bb[jj] = vs[j][tx * 4 + jj];
#pragma unroll
    for (int i = 0; i < 4; ++i)
#pragma unroll
      for (int jj = 0; jj < 4; ++jj) acc[i][jj] += a[i] * bb[jj];
  }
  float* dst = kvb + ((size_t)bh * NKB + m) * DD * DD;
#pragma unroll
  for (int i = 0; i < 4; ++i) {
    float4 val = make_float4(acc[i][0], acc[i][1], acc[i][2], acc[i][3]);
    *reinterpret_cast<float4*>(&dst[(size_t)(ty * 4 + i) * DD + tx * 4]) = val;
  }
}

// ---------------- totals over all key blocks ----------------
// grid: NB*NHH, 256 threads
__global__ void totals_kernel(const float* __restrict__ kvb, const float* __restrict__ ksum,
                              float* __restrict__ kvtot, float* __restrict__ kstot) {
  int bh = blockIdx.x;
  int tid = threadIdx.x;
  for (int i = tid; i < DD * DD; i += 256) {
    float s = 0.f;
    for (int m2 = 0; m2 < NKB; ++m2) s += kvb[((size_t)bh * NKB + m2) * DD * DD + i];
    kvtot[(size_t)bh * DD * DD + i] = s;
  }
  if (tid < DD) {
    float s = 0.f;
    for (int m2 = 0; m2 < NKB; ++m2) s += ksum[((size_t)bh * NKB + m2) * DD + tid];
    kstot[(size_t)bh * DD + tid] = s;
  }
}

// ---------------- fused sparse attention + linear path ----------------
// grid: NB*NHH*NQ ((bh)*NQ+n), 256 threads
__global__ __launch_bounds__(256) void attn_kernel(
    const float* __restrict__ q, const float* __restrict__ k, const float* __restrict__ v,
    const float* __restrict__ kvb, const float* __restrict__ ksum,
    const float* __restrict__ kvtot, const float* __restrict__ kstot,
    const int* __restrict__ lut, const float* __restrict__ plw,
    const float* __restrict__ plb, float* __restrict__ ochan) {
  __shared__ float QT[DD][BLK + 4];  // [d][r] q transposed; later CqT
  __shared__ float KT[DD][BLK + 4];  // [d][c] k transposed; later kvq [dd][e]
  __shared__ float Vs[BLK][DD + 4];  // [kk][e]; later PwT [d][e2]
  __shared__ float Ss[BLK][DD + 1];  // [r][c] scores/p; later o_l, final staging
  __shared__ float rowm[BLK], rowl[BLK], rowsc[BLK], den[BLK], ksq[DD], pbs[DD];
  __shared__ int luts[TT];
  int id = blockIdx.x;
  int n = id % NQ;
  int bh = id / NQ;
  int b = bh / NHH, h = bh % NHH;
  int tid = threadIdx.x;
  int tx = tid & 15, ty = tid >> 4;
  if (tid < TT) luts[tid] = lut[(size_t)id * TT + tid];
  if (tid < BLK) { rowm[tid] = -INFINITY; rowl[tid] = 0.f; }
  const float* qp = q + ((size_t)bh * LL + (size_t)n * BLK) * DD;
  for (int i = tid; i < BLK * DD; i += 256) QT[i & 63][i >> 6] = qp[i];
  __syncthreads();
  float accO[4][4] = {};
  for (int t = 0; t < TT; ++t) {
    int mb = luts[t];
    const float* kp = k + ((size_t)bh * LL + (size_t)mb * BLK) * DD;
    const float* vp = v + ((size_t)bh * LL + (size_t)mb * BLK) * DD;
    for (int i = tid; i < BLK * DD; i += 256) {
      KT[i & 63][i >> 6] = kp[i];
      vs_store:;
      Vs[i >> 6][i & 63] = vp[i];
    }
    __syncthreads();
    float s4[4][4] = {};
#pragma unroll 8
    for (int d2 = 0; d2 < DD; ++d2) {
      float a[4], bb[4];
#pragma unroll
      for (int i = 0; i < 4; ++i) a[i] = QT[d2][ty * 4 + i];
#pragma unroll
      for (int j = 0; j < 4; ++j) bb[j] = KT[d2][tx * 4 + j];
#pragma unroll
      for (int i = 0; i < 4; ++i)
#pragma unroll
        for (int j = 0; j < 4; ++j) s4[i][j] += a[i] * bb[j];
    }
#pragma unroll
    for (int i = 0; i < 4; ++i)
#pragma unroll
      for (int j = 0; j < 4; ++j) Ss[ty * 4 + i][tx * 4 + j] = s4[i][j] * 0.125f;
    __syncthreads();
    if (tid < BLK) {
      int r = tid;
      float mprev = rowm[r];
      float mx = mprev;
#pragma unroll 8
      for (int c = 0; c < BLK; ++c) mx = fmaxf(mx, Ss[r][c]);
      float fac = __expf(mprev - mx);
      float sum = 0.f;
#pragma unroll 8
      for (int c = 0; c < BLK; ++c) { float p = __expf(Ss[r][c] - mx); Ss[r][c] = p; sum += p; }
      rowl[r] = rowl[r] * fac + sum;
      rowm[r] = mx;
      rowsc[r] = fac;
    }
    __syncthreads();
    {
      float f[4];
#pragma unroll
      for (int i = 0; i < 4; ++i) f[i] = rowsc[ty * 4 + i];
#pragma unroll
      for (int i = 0; i < 4; ++i)
#pragma unroll
        for (int j = 0; j < 4; ++j) accO[i][j] *= f[i];
    }
#pragma unroll 4
    for (int kk = 0; kk < BLK; ++kk) {
      float p[4], wv[4];
#pragma unroll
      for (int i = 0; i < 4; ++i) p[i] = Ss[ty * 4 + i][kk];
#pragma unroll
      for (int j = 0; j < 4; ++j) wv[j] = Vs[kk][tx * 4 + j];
#pragma unroll
      for (int i = 0; i < 4; ++i)
#pragma unroll
        for (int j = 0; j < 4; ++j) accO[i][j] += p[i] * wv[j];
    }
    __syncthreads();
  }
  {  // finalize o_s
    float inv[4];
#pragma unroll
    for (int i = 0; i < 4; ++i) inv[i] = 1.0f / rowl[ty * 4 + i];
#pragma unroll
    for (int i = 0; i < 4; ++i)
#pragma unroll
      for (int j = 0; j < 4; ++j) accO[i][j] *= inv[i];
  }
  // ---- linear path ----
  {  // c_q in place in QT (column r handled by 4 threads of one quad)
    int r = tid >> 2, p = tid & 3;
    float mx = -INFINITY;
#pragma unroll
    for (int c = 0; c < 16; ++c) mx = fmaxf(mx, QT[p * 16 + c][r]);
    mx = fmaxf(mx, __shfl_xor(mx, 1));
    mx = fmaxf(mx, __shfl_xor(mx, 2));
    float e[16]; float sum = 0.f;
#pragma unroll
    for (int c = 0; c < 16; ++c) { e[c] = __expf(QT[p * 16 + c][r] - mx); sum += e[c]; }
    sum += __shfl_xor(sum, 1);
    sum += __shfl_xor(sum, 2);
    float inv = 1.0f / sum;
#pragma unroll
    for (int c = 0; c < 16; ++c) QT[p * 16 + c][r] = e[c] * inv;
  }
  const float* kvtp = kvtot + (size_t)bh * DD * DD;
  for (int i = tid; i < DD * DD; i += 256) {
    float s = kvtp[i];
#pragma unroll
    for (int t2 = 0; t2 < TT; ++t2)
      s -= kvb[((size_t)bh * NKB + luts[t2]) * DD * DD + i];
    KT[i >> 6][i & 63] = s;          // kvq[dd][e]
    Vs[i & 63][i >> 6] = plw[i];     // PwT[d][e2] = plw[e2][d]
  }
  if (tid < DD) {
    float s = kstot[(size_t)bh * DD + tid];
#pragma unroll
    for (int t2 = 0; t2 < TT; ++t2)
      s -= ksum[((size_t)bh * NKB + luts[t2]) * DD + tid];
    ksq[tid] = s;
    pbs[tid] = plb[tid];
  }
  __syncthreads();
  float nacc[4][4] = {};
#pragma unroll 8
  for (int d2 = 0; d2 < DD; ++d2) {
    float a[4], bb[4];
#pragma unroll
    for (int i = 0; i < 4; ++i) a[i] = QT[d2][ty * 4 + i];
#pragma unroll
    for (int j = 0; j < 4; ++j) bb[j] = KT[d2][tx * 4 + j];
#pragma unroll
    for (int i = 0; i < 4; ++i)
#pragma unroll
      for (int j = 0; j < 4; ++j) nacc[i][j] += a[i] * bb[j];
  }
  if (tid < BLK) {
    float s = 0.f;
#pragma unroll 8
    for (int d2 = 0; d2 < DD; ++d2) s += QT[d2][tid] * ksq[d2];
    den[tid] = s + 1e-6f;
  }
  __syncthreads();
  {
    float dv[4];
#pragma unroll
    for (int i = 0; i < 4; ++i) dv[i] = 1.0f / den[ty * 4 + i];
#pragma unroll
    for (int i = 0; i < 4; ++i)
#pragma unroll
      for (int j = 0; j < 4; ++j) Ss[ty * 4 + i][tx * 4 + j] = nacc[i][j] * dv[i];
  }
  __syncthreads();
  float facc[4][4];
  {
    float pb[4];
#pragma unroll
    for (int j = 0; j < 4; ++j) pb[j] = pbs[tx * 4 + j];
#pragma unroll
    for (int i = 0; i < 4; ++i)
#pragma unroll
      for (int j = 0; j < 4; ++j) facc[i][j] = accO[i][j] + pb[j];
  }
#pragma unroll 8
  for (int d2 = 0; d2 < DD; ++d2) {
    float p[4], wv[4];
#pragma unroll
    for (int i = 0; i < 4; ++i) p[i] = Ss[ty * 4 + i][d2];
#pragma unroll
    for (int j = 0; j < 4; ++j) wv[j] = Vs[d2][tx * 4 + j];
#pragma unroll
    for (int i = 0; i < 4; ++i)
#pragma unroll
      for (int j = 0; j < 4; ++j) facc[i][j] += p[i] * wv[j];
  }
  __syncthreads();
#pragma unroll
  for (int i = 0; i < 4; ++i)
#pragma unroll
    for (int j = 0; j < 4; ++j) Ss[ty * 4 + i][tx * 4 + j] = facc[i][j];
  __syncthreads();
  // transposed write to ochan (B, C, L)
  float* op = ochan + ((size_t)b * NC + (size_t)h * DD) * LL + (size_t)n * BLK;
  int r2 = tid & 63, chunk = tid >> 6;
#pragma unroll
  for (int s2 = 0; s2 < 16; ++s2) {
    int ch = chunk * 16 + s2;
    op[(size_t)ch * LL + r2] = Ss[r2][ch];
  }
}

// ---------------- out projection GEMM ----------------
// grid: (LL/64, NC/64, NB), 256 threads, 64(co)x64(l) tile
__global__ __launch_bounds__(256) void out_gemm(const float* __restrict__ ochan,
                                                const float* __restrict__ w,
                                                float* __restrict__ out) {
  __shared__ float Os[32][BLK + 4];  // [ci][l]
  __shared__ float Wt[32][BLK + 4];  // [ci][co]
  int l0 = blockIdx.x * 64;
  int co0 = blockIdx.y * 64;
  int b = blockIdx.z;
  int tid = threadIdx.x;
  int tx = tid & 15, ty = tid >> 4;
  float acc[4][4] = {};
  const float* opb = ochan + (size_t)b * NC * LL + l0;
  const float* wp = w + (size_t)co0 * NC;
  int llA = tid & 63, ccA = tid >> 6;
  int j2B = tid & 31, rB = tid >> 5;
  for (int c0 = 0; c0 < NC; c0 += 32) {
#pragma unroll
    for (int s = 0; s < 8; ++s)
      Os[ccA + s * 4][llA] = opb[(size_t)(c0 + ccA + s * 4) * LL + llA];
#pragma unroll
    for (int s = 0; s < 8; ++s)
      Wt[j2B][rB + s * 8] = wp[(size_t)(rB + s * 8) * NC + c0 + j2B];
    __syncthreads();
#pragma unroll
    for (int cc = 0; cc < 32; ++cc) {
      float a[4], bb[4];
#pragma unroll
      for (int i = 0; i < 4; ++i) a[i] = Wt[cc][ty * 4 + i];
#pragma unroll
      for (int j = 0; j < 4; ++j) bb[j] = Os[cc][tx * 4 + j];
#pragma unroll
      for (int i = 0; i < 4; ++i)
#pragma unroll
        for (int j = 0; j < 4; ++j) acc[i][j] += a[i] * bb[j];
    }
    __syncthreads();
  }
  float* dst = out + ((size_t)b * NC + co0) * LL + l0;
#pragma unroll
  for (int i = 0; i < 4; ++i) {
    float4 val = make_float4(acc[i][0], acc[i][1], acc[i][2], acc[i][3]);
    *reinterpret_cast<float4*>(&dst[(size_t)(ty * 4 + i) * LL + tx * 4]) = val;
  }
}

extern "C" void kernel_launch(void* const* d_in, const int* in_sizes, int n_in,
                              void* d_out, int out_size, void* d_ws, size_t ws_size,
                              hipStream_t stream) {
  (void)in_sizes; (void)n_in; (void)out_size; (void)ws_size;
  const float* x = (const float*)d_in[0];
  const float* qkv_w = (const float*)d_in[1];
  const float* out_w = (const float*)d_in[2];
  const float* plw = (const float*)d_in[3];
  const float* plb = (const float*)d_in[4];
  float* out = (float*)d_out;
  float* wsf = (float*)d_ws;
  const size_t QS = (size_t)NB * NHH * LL * DD;  // 8388608
  float* q = wsf;
  float* k = q + QS;
  float* v = k + QS;
  float* ochan = v + QS;       // NB*NC*LL == QS
  float* kvb = ochan + QS;     // NB*NHH*NKB*DD*DD == QS
  float* ksum = kvb + QS;                          // NB*NHH*NKB*DD = 131072
  float* kvtot = ksum + (size_t)NB * NHH * NKB * DD;   // 131072
  float* kstot = kvtot + (size_t)NB * NHH * DD * DD;   // 2048
  float* xb = kstot + (size_t)NB * NHH * DD;           // 131072
  float* qb = xb + (size_t)NB * NC * NQ;               // 131072
  float* kb = qb + (size_t)NB * NHH * NQ * DD;         // 131072
  int* lut = (int*)(kb + (size_t)NB * NHH * NQ * DD);  // 12288 ints

  xb_kernel<<<NB * NC, 64, 0, stream>>>(x, xb);
  qbkb_kernel<<<NB * NQ * NHH, 128, 0, stream>>>(qkv_w, xb, qb, kb);
  topk_kernel<<<NB * NHH * NQ, 64, 0, stream>>>(qb, kb, lut);
  qkv_gemm<<<dim3(LL / 64, 12, NB), 256, 0, stream>>>(x, qkv_w, q, k, v);
  kvb_kernel<<<NB * NHH * NKB, 256, 0, stream>>>(k, v, kvb, ksum);
  totals_kernel<<<NB * NHH, 256, 0, stream>>>(kvb, ksum, kvtot, kstot);
  attn_kernel<<<NB * NHH * NQ, 256, 0, stream>>>(q, k, v, kvb, ksum, kvtot, kstot,
                                                 lut, plw, plb, ochan);
  out_gemm<<<dim3(LL / 64, NC / 64, NB), 256, 0, stream>>>(ochan, out_w, out);
}

// Round 2
// 547.234 us; speedup vs baseline: 1.2964x; 1.2964x over previous
//
#include <hip/hip_runtime.h>
#include <hip/hip_bf16.h>
#include <cmath>

#define NB 8
#define NC 256
#define NHH 4
#define DD 64
#define LL 4096
#define NQ 64
#define NKB 64
#define BLK 64
#define TT 6
#define PAD 72  // f16 row stride: conflict-free b128 frag reads

typedef _Float16 f16;
typedef _Float16 half8 __attribute__((ext_vector_type(8)));
typedef float f32x4 __attribute__((ext_vector_type(4)));
typedef unsigned long long ull;

#define INV2048 4.8828125e-4f

__device__ inline unsigned int pack2(f16 a, f16 b) {
  union { f16 h[2]; unsigned int u; } un;
  un.h[0] = a; un.h[1] = b;
  return un.u;
}

// ---------------- xb: per-block channel means of x ----------------
__global__ void xb_kernel(const float* __restrict__ x, float* __restrict__ xb) {
  int bc = blockIdx.x;
  const float* row = x + (size_t)bc * LL;
  int j = threadIdx.x;
  for (int n = 0; n < NQ; ++n) {
    float v = row[n * BLK + j];
#pragma unroll
    for (int off = 32; off > 0; off >>= 1) v += __shfl_xor(v, off);
    if (j == 0) xb[(size_t)bc * NQ + n] = v * (1.0f / 64.0f);
  }
}

// ---------------- qb/kb: project block means (exact f32, keeps topk stable) --
__global__ void qbkb_kernel(const float* __restrict__ w, const float* __restrict__ xb,
                            float* __restrict__ qb, float* __restrict__ kb) {
  int id = blockIdx.x;
  int h = id % NHH; id /= NHH;
  int n = id % NQ;  int b = id / NQ;
  int t = threadIdx.x;
  int d = t & 63;
  int part = t >> 6;
  const float* wrow = w + (size_t)(part * NC + h * DD + d) * NC;
  const float* xcol = xb + (size_t)b * NC * NQ + n;
  float acc = 0.f;
#pragma unroll 4
  for (int c = 0; c < NC; ++c) acc += wrow[c] * xcol[(size_t)c * NQ];
  float* dst = (part == 0) ? qb : kb;
  dst[(((size_t)b * NHH + h) * NQ + n) * DD + d] = acc;
}

// ---------------- topk ----------------
__global__ void topk_kernel(const float* __restrict__ qb, const float* __restrict__ kb,
                            int* __restrict__ lut) {
  __shared__ float kbs[NKB][DD + 1];
  int id = blockIdx.x;
  int n = id % NQ;
  int bh = id / NQ;
  int m = threadIdx.x;
  const float* kbp = kb + (size_t)bh * NKB * DD;
  for (int i = threadIdx.x; i < NKB * DD; i += 64) kbs[i >> 6][i & 63] = kbp[i];
  __syncthreads();
  const float* qrow = qb + ((size_t)bh * NQ + n) * DD;
  float s = 0.f;
#pragma unroll 8
  for (int d2 = 0; d2 < DD; ++d2) s += qrow[d2] * kbs[m][d2];
  for (int t = 0; t < TT; ++t) {
    float v = s; int i = m;
#pragma unroll
    for (int off = 1; off < 64; off <<= 1) {
      float ov = __shfl_xor(v, off);
      int oi = __shfl_xor(i, off);
      if (ov > v || (ov == v && oi < i)) { v = ov; i = oi; }
    }
    if (m == 0) lut[(size_t)id * TT + t] = i;
    if (m == i) s = -INFINITY;
  }
}

// ---------------- qkv GEMM via split-f16 MFMA ----------------
// C[l][o] = sum_c x[c][l] * w[o][c].  A = X^T staged (rows=l), B = W direct.
__global__ __launch_bounds__(256) void qkv_mfma(const float* __restrict__ x,
                                                const float* __restrict__ wq,
                                                float* __restrict__ q,
                                                float* __restrict__ k,
                                                float* __restrict__ v) {
  __shared__ f16 XH[BLK][PAD], XL[BLK][PAD], WH[BLK][PAD], WL[BLK][PAD];
  int l0 = blockIdx.x * 64;
  int y = blockIdx.y;
  int o0 = y * 64;
  int b = blockIdx.z;
  int tid = threadIdx.x;
  int w = tid >> 6, lane = tid & 63, c16 = lane & 15, g = lane >> 4;
  f32x4 acc[4], acc2[4];
#pragma unroll
  for (int j = 0; j < 4; ++j) { acc[j] = (f32x4){0.f,0.f,0.f,0.f}; acc2[j] = (f32x4){0.f,0.f,0.f,0.f}; }
  const float* xp = x + (size_t)b * NC * LL + l0;
  const float* wp = wq + (size_t)o0 * NC;
  for (int c0 = 0; c0 < NC; c0 += 64) {
    __syncthreads();
    // stage X transposed: XH[l][c]
    for (int it = 0; it < 8; ++it) {
      int idx = it * 256 + tid;
      int ll = idx & 63, cp2 = idx >> 6;
      float a = xp[(size_t)(c0 + 2 * cp2) * LL + ll];
      float bv = xp[(size_t)(c0 + 2 * cp2 + 1) * LL + ll];
      f16 h0 = (f16)a, h1 = (f16)bv;
      *(unsigned int*)&XH[ll][2 * cp2] = pack2(h0, h1);
      *(unsigned int*)&XL[ll][2 * cp2] = pack2((f16)((a - (float)h0) * 2048.f), (f16)((bv - (float)h1) * 2048.f));
    }
    // stage W direct: WH[o][c]
    for (int it = 0; it < 8; ++it) {
      int idx = it * 256 + tid;
      int cp2 = idx & 31, oo = idx >> 5;
      float2 val = *(const float2*)(wp + (size_t)oo * NC + c0 + 2 * cp2);
      f16 h0 = (f16)val.x, h1 = (f16)val.y;
      *(unsigned int*)&WH[oo][2 * cp2] = pack2(h0, h1);
      *(unsigned int*)&WL[oo][2 * cp2] = pack2((f16)((val.x - (float)h0) * 2048.f), (f16)((val.y - (float)h1) * 2048.f));
    }
    __syncthreads();
#pragma unroll
    for (int ks = 0; ks < 2; ++ks) {
      half8 ah = *(const half8*)&XH[w * 16 + c16][ks * 32 + g * 8];
      half8 al = *(const half8*)&XL[w * 16 + c16][ks * 32 + g * 8];
#pragma unroll
      for (int j = 0; j < 4; ++j) {
        half8 bh = *(const half8*)&WH[j * 16 + c16][ks * 32 + g * 8];
        half8 bl = *(const half8*)&WL[j * 16 + c16][ks * 32 + g * 8];
        acc[j]  = __builtin_amdgcn_mfma_f32_16x16x32_f16(ah, bh, acc[j], 0, 0, 0);
        acc2[j] = __builtin_amdgcn_mfma_f32_16x16x32_f16(ah, bl, acc2[j], 0, 0, 0);
        acc2[j] = __builtin_amdgcn_mfma_f32_16x16x32_f16(al, bh, acc2[j], 0, 0, 0);
      }
    }
  }
  int part = y >> 2, h = y & 3;
  float* base = (part == 0) ? q : (part == 1 ? k : v);
  float* dst = base + ((size_t)b * NHH + h) * LL * DD;
#pragma unroll
  for (int j = 0; j < 4; ++j)
#pragma unroll
    for (int r = 0; r < 4; ++r)
      dst[(size_t)(l0 + w * 16 + g * 4 + r) * DD + j * 16 + c16] = acc[j][r] + acc2[j][r] * INV2048;
}

// ---------------- v transpose + split to f16 hi / lo*2048 ----------------
__global__ __launch_bounds__(256) void vsplit_kernel(const float* __restrict__ v,
                                                     f16* __restrict__ vTh, f16* __restrict__ vTl) {
  __shared__ float T[BLK][BLK + 1];
  int id = blockIdx.x;
  int n = id & 63, bh = id >> 6;
  const float* vp = v + ((size_t)bh * LL + (size_t)n * BLK) * DD;
  int tid = threadIdx.x;
  for (int it = 0; it < 16; ++it) {
    int idx = it * 256 + tid;
    int d = idx & 63, pos = idx >> 6;
    T[pos][d] = vp[(size_t)pos * DD + d];
  }
  __syncthreads();
  for (int it = 0; it < 8; ++it) {
    int idx = it * 256 + tid;
    int pp = idx & 31, d = idx >> 5;
    float a = T[2 * pp][d], bb = T[2 * pp + 1][d];
    f16 h0 = (f16)a, h1 = (f16)bb;
    size_t off = ((size_t)bh * DD + d) * LL + (size_t)n * BLK + 2 * pp;
    *(unsigned int*)(vTh + off) = pack2(h0, h1);
    *(unsigned int*)(vTl + off) = pack2((f16)((a - (float)h0) * 2048.f), (f16)((bb - (float)h1) * 2048.f));
  }
}

// ---------------- kvb + ksum per key block (f32, unchanged) ----------------
__global__ __launch_bounds__(256) void kvb_kernel(const float* __restrict__ k,
                                                  const float* __restrict__ v,
                                                  float* __restrict__ kvb,
                                                  float* __restrict__ ksum) {
  __shared__ float ck[BLK][DD + 1];
  __shared__ float vs[BLK][DD + 4];
  int id = blockIdx.x;
  int m = id % NKB;
  int bh = id / NKB;
  int tid = threadIdx.x;
  const float* kp = k + ((size_t)bh * LL + (size_t)m * BLK) * DD;
  const float* vp = v + ((size_t)bh * LL + (size_t)m * BLK) * DD;
  for (int i = tid; i < BLK * DD; i += 256) {
    ck[i >> 6][i & 63] = kp[i];
    vs[i >> 6][i & 63] = vp[i];
  }
  __syncthreads();
  {
    int r = tid >> 2, p = tid & 3;
    float mx = -INFINITY;
#pragma unroll
    for (int c = 0; c < 16; ++c) mx = fmaxf(mx, ck[r][p * 16 + c]);
    mx = fmaxf(mx, __shfl_xor(mx, 1));
    mx = fmaxf(mx, __shfl_xor(mx, 2));
    float e[16]; float sum = 0.f;
#pragma unroll
    for (int c = 0; c < 16; ++c) { e[c] = __expf(ck[r][p * 16 + c] - mx); sum += e[c]; }
    sum += __shfl_xor(sum, 1);
    sum += __shfl_xor(sum, 2);
    float inv = 1.0f / sum;
#pragma unroll
    for (int c = 0; c < 16; ++c) ck[r][p * 16 + c] = e[c] * inv;
  }
  __syncthreads();
  if (tid < DD) {
    float s = 0.f;
#pragma unroll 8
    for (int j = 0; j < BLK; ++j) s += ck[j][tid];
    ksum[((size_t)bh * NKB + m) * DD + tid] = s;
  }
  int tx = tid & 15, ty = tid >> 4;
  float acc[4][4] = {};
#pragma unroll 4
  for (int j = 0; j < BLK; ++j) {
    float a[4], bb[4];
#pragma unroll
    for (int i = 0; i < 4; ++i) a[i] = ck[j][ty * 4 + i];
#pragma unroll
    for (int jj = 0; jj < 4; ++jj) bb[jj] = vs[j][tx * 4 + jj];
#pragma unroll
    for (int i = 0; i < 4; ++i)
#pragma unroll
      for (int jj = 0; jj < 4; ++jj) acc[i][jj] += a[i] * bb[jj];
  }
  float* dst = kvb + ((size_t)bh * NKB + m) * DD * DD;
#pragma unroll
  for (int i = 0; i < 4; ++i) {
    float4 val = make_float4(acc[i][0], acc[i][1], acc[i][2], acc[i][3]);
    *reinterpret_cast<float4*>(&dst[(size_t)(ty * 4 + i) * DD + tx * 4]) = val;
  }
}

// ---------------- totals ----------------
__global__ void totals_kernel(const float* __restrict__ kvb, const float* __restrict__ ksum,
                              float* __restrict__ kvtot, float* __restrict__ kstot) {
  int bh = blockIdx.x;
  int tid = threadIdx.x;
  for (int i = tid; i < DD * DD; i += 256) {
    float s = 0.f;
    for (int m2 = 0; m2 < NKB; ++m2) s += kvb[((size_t)bh * NKB + m2) * DD * DD + i];
    kvtot[(size_t)bh * DD * DD + i] = s;
  }
  if (tid < DD) {
    float s = 0.f;
    for (int m2 = 0; m2 < NKB; ++m2) s += ksum[((size_t)bh * NKB + m2) * DD + tid];
    kstot[(size_t)bh * DD + tid] = s;
  }
}

// ---------------- fused attention, split-f16 MFMA ----------------
// Per (b,h,n): S^T = K·Q^T (C: row=kpos, col=qrow), online softmax per col,
// O^T = V^T·P, then MFMA linear path, store ochan[(B,C,L)] coalesced.
__global__ __launch_bounds__(256) void attn_mfma(
    const float* __restrict__ q, const float* __restrict__ k,
    const f16* __restrict__ vTh, const f16* __restrict__ vTl,
    const float* __restrict__ kvb, const float* __restrict__ ksum,
    const float* __restrict__ kvtot, const float* __restrict__ kstot,
    const int* __restrict__ lut, const float* __restrict__ plw,
    const float* __restrict__ plb, float* __restrict__ ochan) {
  __shared__ f16 QH[BLK][PAD], QL[BLK][PAD];
  __shared__ f16 KH[BLK][PAD], KL[BLK][PAD];
  __shared__ f16 VH[BLK][PAD], VL[BLK][PAD];
  __shared__ f16 PH[BLK][PAD];
  __shared__ float ksq[DD], plbs[DD], dinv[BLK];
  __shared__ int luts[TT];
  int id = blockIdx.x;
  int n = id & 63;
  int bh = id >> 6;
  int b = bh >> 2, h = bh & 3;
  int tid = threadIdx.x;
  int w = tid >> 6, lane = tid & 63, c16 = lane & 15, g = lane >> 4;
  if (tid < TT) luts[tid] = lut[(size_t)id * TT + tid];
  if (tid < DD) plbs[tid] = plb[tid];
  // stage Q (hi, lo*2048)
  const float* qp = q + ((size_t)bh * LL + (size_t)n * BLK) * DD;
  for (int it = 0; it < 8; ++it) {
    int idx = it * 256 + tid;
    int dp = idx & 31, pos = idx >> 5;
    float2 val = *(const float2*)(qp + (size_t)pos * DD + dp * 2);
    f16 h0 = (f16)val.x, h1 = (f16)val.y;
    *(unsigned int*)&QH[pos][dp * 2] = pack2(h0, h1);
    *(unsigned int*)&QL[pos][dp * 2] = pack2((f16)((val.x - (float)h0) * 2048.f), (f16)((val.y - (float)h1) * 2048.f));
  }
  __syncthreads();
  int lu[TT];
#pragma unroll
  for (int t = 0; t < TT; ++t) lu[t] = luts[t];
  half8 bqh[2], bql[2];
#pragma unroll
  for (int ks = 0; ks < 2; ++ks) {
    bqh[ks] = *(const half8*)&QH[w * 16 + c16][ks * 32 + g * 8];
    bql[ks] = *(const half8*)&QL[w * 16 + c16][ks * 32 + g * 8];
  }
  f32x4 acco[4], acco2[4];
#pragma unroll
  for (int j = 0; j < 4; ++j) { acco[j] = (f32x4){0.f,0.f,0.f,0.f}; acco2[j] = (f32x4){0.f,0.f,0.f,0.f}; }
  float m_run = -INFINITY, l_run = 0.f;
  for (int t = 0; t < TT; ++t) {
    int mb = lu[t];
    const float* kp = k + ((size_t)bh * LL + (size_t)mb * BLK) * DD;
    for (int it = 0; it < 8; ++it) {
      int idx = it * 256 + tid;
      int dp = idx & 31, pos = idx >> 5;
      float2 val = *(const float2*)(kp + (size_t)pos * DD + dp * 2);
      f16 h0 = (f16)val.x, h1 = (f16)val.y;
      *(unsigned int*)&KH[pos][dp * 2] = pack2(h0, h1);
      *(unsigned int*)&KL[pos][dp * 2] = pack2((f16)((val.x - (float)h0) * 2048.f), (f16)((val.y - (float)h1) * 2048.f));
    }
    const f16* vhp = vTh + (size_t)bh * DD * LL + (size_t)mb * BLK;
    const f16* vlp = vTl + (size_t)bh * DD * LL + (size_t)mb * BLK;
    for (int it = 0; it < 8; ++it) {
      int idx = it * 256 + tid;
      int pp = idx & 31, d = idx >> 5;
      *(unsigned int*)&VH[d][pp * 2] = *(const unsigned int*)(vhp + (size_t)d * LL + pp * 2);
      *(unsigned int*)&VL[d][pp * 2] = *(const unsigned int*)(vlp + (size_t)d * LL + pp * 2);
    }
    __syncthreads();
    // QK^T
    float p[4][4];
    float mx = m_run;
#pragma unroll
    for (int i = 0; i < 4; ++i) {
      f32x4 acc = {0.f, 0.f, 0.f, 0.f};
      f32x4 accc = {0.f, 0.f, 0.f, 0.f};
#pragma unroll
      for (int ks = 0; ks < 2; ++ks) {
        half8 ah = *(const half8*)&KH[i * 16 + c16][ks * 32 + g * 8];
        half8 al = *(const half8*)&KL[i * 16 + c16][ks * 32 + g * 8];
        acc  = __builtin_amdgcn_mfma_f32_16x16x32_f16(ah, bqh[ks], acc, 0, 0, 0);
        accc = __builtin_amdgcn_mfma_f32_16x16x32_f16(ah, bql[ks], accc, 0, 0, 0);
        accc = __builtin_amdgcn_mfma_f32_16x16x32_f16(al, bqh[ks], accc, 0, 0, 0);
      }
#pragma unroll
      for (int r = 0; r < 4; ++r) {
        p[i][r] = (acc[r] + accc[r] * INV2048) * 0.125f;
        mx = fmaxf(mx, p[i][r]);
      }
    }
    mx = fmaxf(mx, __shfl_xor(mx, 16));
    mx = fmaxf(mx, __shfl_xor(mx, 32));
    float fac = __expf(m_run - mx);
    float rs = 0.f;
#pragma unroll
    for (int i = 0; i < 4; ++i)
#pragma unroll
      for (int r = 0; r < 4; ++r) { p[i][r] = __expf(p[i][r] - mx); rs += p[i][r]; }
    rs += __shfl_xor(rs, 16);
    rs += __shfl_xor(rs, 32);
    l_run = l_run * fac + rs;
    m_run = mx;
#pragma unroll
    for (int j = 0; j < 4; ++j)
#pragma unroll
      for (int r = 0; r < 4; ++r) { acco[j][r] *= fac; acco2[j][r] *= fac; }
    // write P (single f16; bounded [0,1], feeds only bounded o_s)
#pragma unroll
    for (int i = 0; i < 4; ++i) {
      ull uu = (ull)pack2((f16)p[i][0], (f16)p[i][1]) | ((ull)pack2((f16)p[i][2], (f16)p[i][3]) << 32);
      *(ull*)&PH[w * 16 + c16][i * 16 + g * 4] = uu;
    }
    // PV
#pragma unroll
    for (int ks = 0; ks < 2; ++ks) {
      half8 pb = *(const half8*)&PH[w * 16 + c16][ks * 32 + g * 8];
#pragma unroll
      for (int j = 0; j < 4; ++j) {
        half8 vh = *(const half8*)&VH[j * 16 + c16][ks * 32 + g * 8];
        half8 vl = *(const half8*)&VL[j * 16 + c16][ks * 32 + g * 8];
        acco[j]  = __builtin_amdgcn_mfma_f32_16x16x32_f16(vh, pb, acco[j], 0, 0, 0);
        acco2[j] = __builtin_amdgcn_mfma_f32_16x16x32_f16(vl, pb, acco2[j], 0, 0, 0);
      }
    }
    __syncthreads();
  }
  // normalize o_s (combine hi + lo/2048)
  float linv = 1.f / l_run;
#pragma unroll
  for (int j = 0; j < 4; ++j)
#pragma unroll
    for (int r = 0; r < 4; ++r) acco[j][r] = (acco[j][r] + acco2[j][r] * INV2048) * linv;
  // ---- linear path ----
  // A1: ksq, Cq -> VH/VL, kvq^T -> KH/KL
  if (tid < DD) {
    float s = kstot[(size_t)bh * DD + tid];
#pragma unroll
    for (int t2 = 0; t2 < TT; ++t2) s -= ksum[((size_t)bh * NKB + lu[t2]) * DD + tid];
    ksq[tid] = s;
  }
  int cr = tid >> 2, cp = tid & 3;
  float cq[16];
  {
    float mx2 = -INFINITY;
#pragma unroll
    for (int c = 0; c < 16; ++c) {
      cq[c] = (float)QH[cr][cp * 16 + c] + (float)QL[cr][cp * 16 + c] * INV2048;
      mx2 = fmaxf(mx2, cq[c]);
    }
    mx2 = fmaxf(mx2, __shfl_xor(mx2, 1));
    mx2 = fmaxf(mx2, __shfl_xor(mx2, 2));
    float sum = 0.f;
#pragma unroll
    for (int c = 0; c < 16; ++c) { cq[c] = __expf(cq[c] - mx2); sum += cq[c]; }
    sum += __shfl_xor(sum, 1);
    sum += __shfl_xor(sum, 2);
    float inv = 1.f / sum;
#pragma unroll
    for (int c = 0; c < 16; ++c) cq[c] *= inv;
  }
#pragma unroll
  for (int c = 0; c < 8; ++c) {
    f16 h0 = (f16)cq[2 * c], h1 = (f16)cq[2 * c + 1];
    *(unsigned int*)&VH[cr][cp * 16 + 2 * c] = pack2(h0, h1);
    *(unsigned int*)&VL[cr][cp * 16 + 2 * c] = pack2((f16)((cq[2 * c] - (float)h0) * 2048.f), (f16)((cq[2 * c + 1] - (float)h1) * 2048.f));
  }
  {
    const float* kvtp = kvtot + (size_t)bh * DD * DD;
    const float* kvbp = kvb + (size_t)bh * NKB * DD * DD;
    for (int it = 0; it < 16; ++it) {
      int idx = it * 256 + tid;
      int e = idx & 63, dd2 = idx >> 6;
      float s = kvtp[dd2 * DD + e];
#pragma unroll
      for (int t2 = 0; t2 < TT; ++t2) s -= kvbp[(size_t)lu[t2] * DD * DD + dd2 * DD + e];
      f16 sh = (f16)s;
      KH[e][dd2] = sh;
      KL[e][dd2] = (f16)((s - (float)sh) * 2048.f);
    }
  }
  __syncthreads();
  // A2: den (f32, exact cq values) + num MFMA
  {
    float dpart = 0.f;
#pragma unroll
    for (int c = 0; c < 16; ++c) dpart += cq[c] * ksq[cp * 16 + c];
    dpart += __shfl_xor(dpart, 1);
    dpart += __shfl_xor(dpart, 2);
    if (cp == 0) dinv[cr] = 1.f / (dpart + 1e-6f);
  }
  f32x4 accn[4], accn2[4];
  {
    half8 cqh[2], cql[2];
#pragma unroll
    for (int ks = 0; ks < 2; ++ks) {
      cqh[ks] = *(const half8*)&VH[w * 16 + c16][ks * 32 + g * 8];
      cql[ks] = *(const half8*)&VL[w * 16 + c16][ks * 32 + g * 8];
    }
#pragma unroll
    for (int j = 0; j < 4; ++j) {
      f32x4 acc = {0.f, 0.f, 0.f, 0.f};
      f32x4 accc = {0.f, 0.f, 0.f, 0.f};
#pragma unroll
      for (int ks = 0; ks < 2; ++ks) {
        half8 ah = *(const half8*)&KH[j * 16 + c16][ks * 32 + g * 8];
        half8 al = *(const half8*)&KL[j * 16 + c16][ks * 32 + g * 8];
        acc  = __builtin_amdgcn_mfma_f32_16x16x32_f16(ah, cqh[ks], acc, 0, 0, 0);
        accc = __builtin_amdgcn_mfma_f32_16x16x32_f16(ah, cql[ks], accc, 0, 0, 0);
        accc = __builtin_amdgcn_mfma_f32_16x16x32_f16(al, cqh[ks], accc, 0, 0, 0);
      }
      accn[j] = acc; accn2[j] = accc;
    }
  }
  __syncthreads();
  // A3: o_l = num*dinv -> Bol (hi->PH, lo*2048->KH), final MFMA with plw
  float di = dinv[w * 16 + c16];
#pragma unroll
  for (int j = 0; j < 4; ++j) {
    float o0 = (accn[j][0] + accn2[j][0] * INV2048) * di;
    float o1 = (accn[j][1] + accn2[j][1] * INV2048) * di;
    float o2 = (accn[j][2] + accn2[j][2] * INV2048) * di;
    float o3 = (accn[j][3] + accn2[j][3] * INV2048) * di;
    f16 h0 = (f16)o0, h1 = (f16)o1, h2 = (f16)o2, h3 = (f16)o3;
    ull uh = (ull)pack2(h0, h1) | ((ull)pack2(h2, h3) << 32);
    ull ul = (ull)pack2((f16)((o0 - (float)h0) * 2048.f), (f16)((o1 - (float)h1) * 2048.f))
           | ((ull)pack2((f16)((o2 - (float)h2) * 2048.f), (f16)((o3 - (float)h3) * 2048.f)) << 32);
    *(ull*)&PH[w * 16 + c16][j * 16 + g * 4] = uh;
    *(ull*)&KH[w * 16 + c16][j * 16 + g * 4] = ul;
  }
  f32x4 accf2[4];
#pragma unroll
  for (int j = 0; j < 4; ++j) accf2[j] = (f32x4){0.f,0.f,0.f,0.f};
#pragma unroll
  for (int ks = 0; ks < 2; ++ks) {
    half8 bolh = *(const half8*)&PH[w * 16 + c16][ks * 32 + g * 8];
    half8 boll = *(const half8*)&KH[w * 16 + c16][ks * 32 + g * 8];
#pragma unroll
    for (int j = 0; j < 4; ++j) {
      const float* pw = plw + (size_t)(j * 16 + c16) * DD + ks * 32 + g * 8;
      float4 w0 = *(const float4*)pw;
      float4 w1 = *(const float4*)(pw + 4);
      half8 awh, awl;
      awh[0] = (f16)w0.x; awl[0] = (f16)((w0.x - (float)awh[0]) * 2048.f);
      awh[1] = (f16)w0.y; awl[1] = (f16)((w0.y - (float)awh[1]) * 2048.f);
      awh[2] = (f16)w0.z; awl[2] = (f16)((w0.z - (float)awh[2]) * 2048.f);
      awh[3] = (f16)w0.w; awl[3] = (f16)((w0.w - (float)awh[3]) * 2048.f);
      awh[4] = (f16)w1.x; awl[4] = (f16)((w1.x - (float)awh[4]) * 2048.f);
      awh[5] = (f16)w1.y; awl[5] = (f16)((w1.y - (float)awh[5]) * 2048.f);
      awh[6] = (f16)w1.z; awl[6] = (f16)((w1.z - (float)awh[6]) * 2048.f);
      awh[7] = (f16)w1.w; awl[7] = (f16)((w1.w - (float)awh[7]) * 2048.f);
      acco[j]  = __builtin_amdgcn_mfma_f32_16x16x32_f16(awh, bolh, acco[j], 0, 0, 0);
      accf2[j] = __builtin_amdgcn_mfma_f32_16x16x32_f16(awh, boll, accf2[j], 0, 0, 0);
      accf2[j] = __builtin_amdgcn_mfma_f32_16x16x32_f16(awl, bolh, accf2[j], 0, 0, 0);
    }
  }
#pragma unroll
  for (int j = 0; j < 4; ++j)
#pragma unroll
    for (int r = 0; r < 4; ++r) {
      int e2 = j * 16 + g * 4 + r;
      float outv = acco[j][r] + accf2[j][r] * INV2048 + plbs[e2];
      ochan[((size_t)b * NC + h * DD + e2) * LL + (size_t)n * BLK + w * 16 + c16] = outv;
    }
}

// ---------------- out projection via split-f16 MFMA ----------------
// C[o][l] = sum_c wo[o][c] * ochan[c][l].  A = W direct, B = ochan^T staged.
__global__ __launch_bounds__(256) void out_mfma(const float* __restrict__ ochan,
                                                const float* __restrict__ wo,
                                                float* __restrict__ out) {
  __shared__ f16 OH[BLK][PAD], OL[BLK][PAD], WH[BLK][PAD], WL[BLK][PAD];
  int l0 = blockIdx.x * 64;
  int o0 = blockIdx.y * 64;
  int b = blockIdx.z;
  int tid = threadIdx.x;
  int w = tid >> 6, lane = tid & 63, c16 = lane & 15, g = lane >> 4;
  f32x4 acc[4], acc2[4];
#pragma unroll
  for (int j = 0; j < 4; ++j) { acc[j] = (f32x4){0.f,0.f,0.f,0.f}; acc2[j] = (f32x4){0.f,0.f,0.f,0.f}; }
  const float* op = ochan + (size_t)b * NC * LL + l0;
  const float* wp = wo + (size_t)o0 * NC;
  for (int c0 = 0; c0 < NC; c0 += 64) {
    __syncthreads();
    for (int it = 0; it < 8; ++it) {
      int idx = it * 256 + tid;
      int ll = idx & 63, cp2 = idx >> 6;
      float a = op[(size_t)(c0 + 2 * cp2) * LL + ll];
      float bv = op[(size_t)(c0 + 2 * cp2 + 1) * LL + ll];
      f16 h0 = (f16)a, h1 = (f16)bv;
      *(unsigned int*)&OH[ll][2 * cp2] = pack2(h0, h1);
      *(unsigned int*)&OL[ll][2 * cp2] = pack2((f16)((a - (float)h0) * 2048.f), (f16)((bv - (float)h1) * 2048.f));
    }
    for (int it = 0; it < 8; ++it) {
      int idx = it * 256 + tid;
      int cp2 = idx & 31, oo = idx >> 5;
      float2 val = *(const float2*)(wp + (size_t)oo * NC + c0 + 2 * cp2);
      f16 h0 = (f16)val.x, h1 = (f16)val.y;
      *(unsigned int*)&WH[oo][2 * cp2] = pack2(h0, h1);
      *(unsigned int*)&WL[oo][2 * cp2] = pack2((f16)((val.x - (float)h0) * 2048.f), (f16)((val.y - (float)h1) * 2048.f));
    }
    __syncthreads();
#pragma unroll
    for (int ks = 0; ks < 2; ++ks) {
      half8 awh = *(const half8*)&WH[w * 16 + c16][ks * 32 + g * 8];
      half8 awl = *(const half8*)&WL[w * 16 + c16][ks * 32 + g * 8];
#pragma unroll
      for (int j = 0; j < 4; ++j) {
        half8 bh = *(const half8*)&OH[j * 16 + c16][ks * 32 + g * 8];
        half8 bl = *(const half8*)&OL[j * 16 + c16][ks * 32 + g * 8];
        acc[j]  = __builtin_amdgcn_mfma_f32_16x16x32_f16(awh, bh, acc[j], 0, 0, 0);
        acc2[j] = __builtin_amdgcn_mfma_f32_16x16x32_f16(awh, bl, acc2[j], 0, 0, 0);
        acc2[j] = __builtin_amdgcn_mfma_f32_16x16x32_f16(awl, bh, acc2[j], 0, 0, 0);
      }
    }
  }
#pragma unroll
  for (int j = 0; j < 4; ++j)
#pragma unroll
    for (int r = 0; r < 4; ++r)
      out[((size_t)b * NC + o0 + w * 16 + g * 4 + r) * LL + l0 + j * 16 + c16] = acc[j][r] + acc2[j][r] * INV2048;
}

extern "C" void kernel_launch(void* const* d_in, const int* in_sizes, int n_in,
                              void* d_out, int out_size, void* d_ws, size_t ws_size,
                              hipStream_t stream) {
  (void)in_sizes; (void)n_in; (void)out_size; (void)ws_size;
  const float* x = (const float*)d_in[0];
  const float* qkv_w = (const float*)d_in[1];
  const float* out_w = (const float*)d_in[2];
  const float* plw = (const float*)d_in[3];
  const float* plb = (const float*)d_in[4];
  float* out = (float*)d_out;
  float* wsf = (float*)d_ws;
  const size_t QS = (size_t)NB * NHH * LL * DD;  // 8388608
  float* q = wsf;
  float* k = q + QS;
  float* v = k + QS;
  float* ochan = v + QS;
  float* kvb = ochan + QS;
  f16* vTh = (f16*)(kvb + QS);            // QS f16 = QS/2 floats
  f16* vTl = (f16*)(kvb + QS + QS / 2);
  float* ksum = kvb + QS + QS;            // after both f16 arrays
  float* kvtot = ksum + (size_t)NB * NHH * NKB * DD;
  float* kstot = kvtot + (size_t)NB * NHH * DD * DD;
  float* xb = kstot + (size_t)NB * NHH * DD;
  float* qb = xb + (size_t)NB * NC * NQ;
  float* kb = qb + (size_t)NB * NHH * NQ * DD;
  int* lut = (int*)(kb + (size_t)NB * NHH * NQ * DD);

  xb_kernel<<<NB * NC, 64, 0, stream>>>(x, xb);
  qbkb_kernel<<<NB * NQ * NHH, 128, 0, stream>>>(qkv_w, xb, qb, kb);
  topk_kernel<<<NB * NHH * NQ, 64, 0, stream>>>(qb, kb, lut);
  qkv_mfma<<<dim3(LL / 64, 12, NB), 256, 0, stream>>>(x, qkv_w, q, k, v);
  vsplit_kernel<<<NB * NHH * NQ, 256, 0, stream>>>(v, vTh, vTl);
  kvb_kernel<<<NB * NHH * NKB, 256, 0, stream>>>(k, v, kvb, ksum);
  totals_kernel<<<NB * NHH, 256, 0, stream>>>(kvb, ksum, kvtot, kstot);
  attn_mfma<<<NB * NHH * NQ, 256, 0, stream>>>(q, k, vTh, vTl, kvb, ksum, kvtot, kstot,
                                               lut, plw, plb, ochan);
  out_mfma<<<dim3(LL / 64, NC / 64, NB), 256, 0, stream>>>(ochan, out_w, out);
}

// Round 3
// 325.497 us; speedup vs baseline: 2.1795x; 1.6812x over previous
//
#include <hip/hip_runtime.h>
#include <hip/hip_bf16.h>
#include <cmath>

#define NB 8
#define NC 256
#define NHH 4
#define DD 64
#define LL 4096
#define NQ 64
#define NKB 64
#define BLK 64
#define TT 6
#define PAD 72  // f16 row stride (144B = 9*16B): 16B-aligned b128 ops

typedef _Float16 f16;
typedef _Float16 half8 __attribute__((ext_vector_type(8)));
typedef float f32x4 __attribute__((ext_vector_type(4)));
typedef unsigned int uint4v __attribute__((ext_vector_type(4)));
typedef unsigned long long ull;

#define INV2048 4.8828125e-4f

union H4 { f16 h[4]; ull u; };
union H2 { f16 h[2]; unsigned int u; };

#define MFMA16(A, B, C) __builtin_amdgcn_mfma_f32_16x16x32_f16(A, B, C, 0, 0, 0)

// ---------------- xb: per-block channel means of x ----------------
__global__ void xb_kernel(const float* __restrict__ x, float* __restrict__ xb) {
  int bc = blockIdx.x;
  const float* row = x + (size_t)bc * LL;
  int j = threadIdx.x;
  for (int n = 0; n < NQ; ++n) {
    float v = row[n * BLK + j];
#pragma unroll
    for (int off = 32; off > 0; off >>= 1) v += __shfl_xor(v, off);
    if (j == 0) xb[(size_t)bc * NQ + n] = v * (1.0f / 64.0f);
  }
}

// ---------------- qb/kb: project block means (exact f32 topk path) ----------
__global__ void qbkb_kernel(const float* __restrict__ w, const float* __restrict__ xb,
                            float* __restrict__ qb, float* __restrict__ kb) {
  int id = blockIdx.x;
  int h = id % NHH; id /= NHH;
  int n = id % NQ;  int b = id / NQ;
  int t = threadIdx.x;
  int d = t & 63;
  int part = t >> 6;
  const float* wrow = w + (size_t)(part * NC + h * DD + d) * NC;
  const float* xcol = xb + (size_t)b * NC * NQ + n;
  float acc = 0.f;
#pragma unroll 4
  for (int c = 0; c < NC; ++c) acc += wrow[c] * xcol[(size_t)c * NQ];
  float* dst = (part == 0) ? qb : kb;
  dst[(((size_t)b * NHH + h) * NQ + n) * DD + d] = acc;
}

// ---------------- topk ----------------
__global__ void topk_kernel(const float* __restrict__ qb, const float* __restrict__ kb,
                            int* __restrict__ lut) {
  __shared__ float kbs[NKB][DD + 1];
  int id = blockIdx.x;
  int n = id % NQ;
  int bh = id / NQ;
  int m = threadIdx.x;
  const float* kbp = kb + (size_t)bh * NKB * DD;
  for (int i = threadIdx.x; i < NKB * DD; i += 64) kbs[i >> 6][i & 63] = kbp[i];
  __syncthreads();
  const float* qrow = qb + ((size_t)bh * NQ + n) * DD;
  float s = 0.f;
#pragma unroll 8
  for (int d2 = 0; d2 < DD; ++d2) s += qrow[d2] * kbs[m][d2];
  for (int t = 0; t < TT; ++t) {
    float v = s; int i = m;
#pragma unroll
    for (int off = 1; off < 64; off <<= 1) {
      float ov = __shfl_xor(v, off);
      int oi = __shfl_xor(i, off);
      if (ov > v || (ov == v && oi < i)) { v = ov; i = oi; }
    }
    if (m == 0) lut[(size_t)id * TT + t] = i;
    if (m == i) s = -INFINITY;
  }
}

// ---------------- generic f32 -> f16 hi/lo split ----------------
__global__ void split_kernel(const float* __restrict__ src, f16* __restrict__ dh,
                             f16* __restrict__ dl, int n) {
  int i = (blockIdx.x * 256 + threadIdx.x) * 4;
  if (i >= n) return;
  float4 v = *(const float4*)(src + i);
  H4 hh, ll;
  hh.h[0] = (f16)v.x; ll.h[0] = (f16)((v.x - (float)hh.h[0]) * 2048.f);
  hh.h[1] = (f16)v.y; ll.h[1] = (f16)((v.y - (float)hh.h[1]) * 2048.f);
  hh.h[2] = (f16)v.z; ll.h[2] = (f16)((v.z - (float)hh.h[2]) * 2048.f);
  hh.h[3] = (f16)v.w; ll.h[3] = (f16)((v.w - (float)hh.h[3]) * 2048.f);
  *(ull*)(dh + i) = hh.u;
  *(ull*)(dl + i) = ll.u;
}

// ---------------- x transpose + split: x[b][c][l] -> xT[b][l][c] hi/lo ------
__global__ __launch_bounds__(256) void xsplit_kernel(const float* __restrict__ x,
                                                     f16* __restrict__ xh, f16* __restrict__ xl) {
  __shared__ float T[64][65];
  int l0 = blockIdx.x * 64, c0 = blockIdx.y * 64, b = blockIdx.z;
  int tid = threadIdx.x;
  for (int it = 0; it < 16; ++it) {
    int idx = it * 256 + tid; int c = idx >> 6, l = idx & 63;
    T[c][l] = x[((size_t)b * NC + c0 + c) * LL + l0 + l];
  }
  __syncthreads();
  for (int it = 0; it < 4; ++it) {
    int idx = it * 256 + tid; int l = idx >> 4, cq = idx & 15;
    float a0 = T[cq * 4 + 0][l], a1 = T[cq * 4 + 1][l], a2 = T[cq * 4 + 2][l], a3 = T[cq * 4 + 3][l];
    H4 hh, ll;
    hh.h[0] = (f16)a0; ll.h[0] = (f16)((a0 - (float)hh.h[0]) * 2048.f);
    hh.h[1] = (f16)a1; ll.h[1] = (f16)((a1 - (float)hh.h[1]) * 2048.f);
    hh.h[2] = (f16)a2; ll.h[2] = (f16)((a2 - (float)hh.h[2]) * 2048.f);
    hh.h[3] = (f16)a3; ll.h[3] = (f16)((a3 - (float)hh.h[3]) * 2048.f);
    size_t off = ((size_t)b * LL + l0 + l) * NC + c0 + cq * 4;
    *(ull*)(xh + off) = hh.u;
    *(ull*)(xl + off) = ll.u;
  }
}

// ---------------- qkv GEMM: A=W (global frags), B=X^T (LDS) -----------------
// C[d][l]; outputs q/k/v as f16 hi/lo in [bh][l][d]
__global__ __launch_bounds__(256) void qkv_mfma(
    const f16* __restrict__ xh, const f16* __restrict__ xl,
    const f16* __restrict__ wh, const f16* __restrict__ wl,
    f16* __restrict__ qh, f16* __restrict__ ql,
    f16* __restrict__ kh, f16* __restrict__ kl,
    f16* __restrict__ vh, f16* __restrict__ vl) {
  __shared__ f16 XH[BLK][PAD], XL[BLK][PAD];
  int L = blockIdx.x;
  int b = L & 7;            // xcd-pinned batch
  int t = L >> 3;
  int l0 = (t / 12) * 64;
  int y = t % 12;
  int part = y >> 2, h = y & 3;
  int tid = threadIdx.x;
  int w = tid >> 6, lane = tid & 63, c16 = lane & 15, g = lane >> 4;
  f32x4 acc[4], acc2[4];
#pragma unroll
  for (int j = 0; j < 4; ++j) { acc[j] = (f32x4){0.f,0.f,0.f,0.f}; acc2[j] = (f32x4){0.f,0.f,0.f,0.f}; }
  size_t wbase = (size_t)(part * NC + h * DD + w * 16 + c16) * NC;
  for (int c0 = 0; c0 < NC; c0 += 64) {
    __syncthreads();
#pragma unroll
    for (int it = 0; it < 2; ++it) {
      int idx = it * 256 + tid; int pos = idx >> 3, dp8 = idx & 7;
      size_t gsrc = ((size_t)b * LL + l0 + pos) * NC + c0 + dp8 * 8;
      *(uint4v*)&XH[pos][dp8 * 8] = *(const uint4v*)(xh + gsrc);
      *(uint4v*)&XL[pos][dp8 * 8] = *(const uint4v*)(xl + gsrc);
    }
    __syncthreads();
#pragma unroll
    for (int ks = 0; ks < 2; ++ks) {
      half8 awh = *(const half8*)(wh + wbase + c0 + ks * 32 + g * 8);
      half8 awl = *(const half8*)(wl + wbase + c0 + ks * 32 + g * 8);
#pragma unroll
      for (int j = 0; j < 4; ++j) {
        half8 bxh = *(const half8*)&XH[j * 16 + c16][ks * 32 + g * 8];
        half8 bxl = *(const half8*)&XL[j * 16 + c16][ks * 32 + g * 8];
        acc[j]  = MFMA16(awh, bxh, acc[j]);
        acc2[j] = MFMA16(awh, bxl, acc2[j]);
        acc2[j] = MFMA16(awl, bxh, acc2[j]);
      }
    }
  }
  f16* dh = (part == 0) ? qh : (part == 1 ? kh : vh);
  f16* dl = (part == 0) ? ql : (part == 1 ? kl : vl);
#pragma unroll
  for (int j = 0; j < 4; ++j) {
    H4 hh, ll;
#pragma unroll
    for (int r = 0; r < 4; ++r) {
      float v = acc[j][r] + acc2[j][r] * INV2048;
      hh.h[r] = (f16)v;
      ll.h[r] = (f16)((v - (float)hh.h[r]) * 2048.f);
    }
    size_t off = (((size_t)b * NHH + h) * LL + l0 + j * 16 + c16) * DD + w * 16 + g * 4;
    *(ull*)(dh + off) = hh.u;
    *(ull*)(dl + off) = ll.u;
  }
}

// ---------------- v transpose (f16): vh[bh][l][d] -> vT[bh][d][l] -----------
__global__ __launch_bounds__(256) void vtrans_kernel(const f16* __restrict__ vh,
                                                     f16* __restrict__ vT) {
  __shared__ f16 T[64][PAD];
  int id = blockIdx.x; int n = id & 63, bh = id >> 6;
  const f16* vp = vh + ((size_t)bh * LL + (size_t)n * BLK) * DD;
  int tid = threadIdx.x;
#pragma unroll
  for (int it = 0; it < 2; ++it) {
    int idx = it * 256 + tid; int pos = idx >> 3, dp8 = idx & 7;
    *(uint4v*)&T[pos][dp8 * 8] = *(const uint4v*)(vp + (size_t)pos * DD + dp8 * 8);
  }
  __syncthreads();
#pragma unroll
  for (int it = 0; it < 4; ++it) {
    int idx = it * 256 + tid; int d = idx >> 4, p4 = (idx & 15) * 4;
    H4 hh;
    hh.h[0] = T[p4 + 0][d]; hh.h[1] = T[p4 + 1][d]; hh.h[2] = T[p4 + 2][d]; hh.h[3] = T[p4 + 3][d];
    *(ull*)(vT + ((size_t)bh * DD + d) * LL + (size_t)n * BLK + p4) = hh.u;
  }
}

// ---------------- kvb + ksum per key block (f32 compute) ----------------
__global__ __launch_bounds__(256) void kvb_kernel(
    const f16* __restrict__ khg, const f16* __restrict__ klg,
    const f16* __restrict__ vhg, const f16* __restrict__ vlg,
    float* __restrict__ kvb, float* __restrict__ ksum) {
  __shared__ float ck[BLK][DD + 1];
  __shared__ float vs[BLK][DD + 4];
  int id = blockIdx.x;
  int m = id % NKB;
  int bh = id / NKB;
  int tid = threadIdx.x;
  int r = tid >> 2, p = tid & 3;
  size_t base = ((size_t)bh * LL + (size_t)m * BLK + r) * DD + p * 16;
  {
    half8 a = *(const half8*)(khg + base), a2 = *(const half8*)(khg + base + 8);
    half8 b1 = *(const half8*)(klg + base), b2 = *(const half8*)(klg + base + 8);
#pragma unroll
    for (int c = 0; c < 8; ++c) {
      ck[r][p * 16 + c] = (float)a[c] + (float)b1[c] * INV2048;
      ck[r][p * 16 + 8 + c] = (float)a2[c] + (float)b2[c] * INV2048;
    }
    half8 va = *(const half8*)(vhg + base), va2 = *(const half8*)(vhg + base + 8);
    half8 vb = *(const half8*)(vlg + base), vb2 = *(const half8*)(vlg + base + 8);
#pragma unroll
    for (int c = 0; c < 8; ++c) {
      vs[r][p * 16 + c] = (float)va[c] + (float)vb[c] * INV2048;
      vs[r][p * 16 + 8 + c] = (float)va2[c] + (float)vb2[c] * INV2048;
    }
  }
  __syncthreads();
  {
    float mx = -INFINITY;
#pragma unroll
    for (int c = 0; c < 16; ++c) mx = fmaxf(mx, ck[r][p * 16 + c]);
    mx = fmaxf(mx, __shfl_xor(mx, 1));
    mx = fmaxf(mx, __shfl_xor(mx, 2));
    float e[16]; float sum = 0.f;
#pragma unroll
    for (int c = 0; c < 16; ++c) { e[c] = __expf(ck[r][p * 16 + c] - mx); sum += e[c]; }
    sum += __shfl_xor(sum, 1);
    sum += __shfl_xor(sum, 2);
    float inv = 1.0f / sum;
#pragma unroll
    for (int c = 0; c < 16; ++c) ck[r][p * 16 + c] = e[c] * inv;
  }
  __syncthreads();
  if (tid < DD) {
    float s = 0.f;
#pragma unroll 8
    for (int j = 0; j < BLK; ++j) s += ck[j][tid];
    ksum[((size_t)bh * NKB + m) * DD + tid] = s;
  }
  int tx = tid & 15, ty = tid >> 4;
  float acc[4][4] = {};
#pragma unroll 4
  for (int j = 0; j < BLK; ++j) {
    float a[4], bb[4];
#pragma unroll
    for (int i = 0; i < 4; ++i) a[i] = ck[j][ty * 4 + i];
#pragma unroll
    for (int jj = 0; jj < 4; ++jj) bb[jj] = vs[j][tx * 4 + jj];
#pragma unroll
    for (int i = 0; i < 4; ++i)
#pragma unroll
      for (int jj = 0; jj < 4; ++jj) acc[i][jj] += a[i] * bb[jj];
  }
  float* dst = kvb + ((size_t)bh * NKB + m) * DD * DD;
#pragma unroll
  for (int i = 0; i < 4; ++i) {
    float4 val = make_float4(acc[i][0], acc[i][1], acc[i][2], acc[i][3]);
    *reinterpret_cast<float4*>(&dst[(size_t)(ty * 4 + i) * DD + tx * 4]) = val;
  }
}

// ---------------- totals (parallelized: 512 blocks) ----------------
__global__ void totals_kernel(const float* __restrict__ kvb, const float* __restrict__ ksum,
                              float* __restrict__ kvtot, float* __restrict__ kstot) {
  int bi = blockIdx.x;
  int bh = bi >> 4, s = bi & 15;
  int tid = threadIdx.x;
  int i = s * 256 + tid;
  float acc = 0.f;
  const float* src = kvb + (size_t)bh * NKB * DD * DD + i;
  for (int m2 = 0; m2 < NKB; ++m2) acc += src[(size_t)m2 * DD * DD];
  kvtot[(size_t)bh * DD * DD + i] = acc;
  if (s == 0 && tid < DD) {
    float ss = 0.f;
    for (int m2 = 0; m2 < NKB; ++m2) ss += ksum[((size_t)bh * NKB + m2) * DD + tid];
    kstot[(size_t)bh * DD + tid] = ss;
  }
}

// ---------------- fused attention ----------------
__global__ __launch_bounds__(256) void attn_mfma(
    const f16* __restrict__ qh_g, const f16* __restrict__ ql_g,
    const f16* __restrict__ kh_g, const f16* __restrict__ kl_g,
    const f16* __restrict__ vT_g,
    const float* __restrict__ kvb, const float* __restrict__ ksum,
    const float* __restrict__ kvtot, const float* __restrict__ kstot,
    const int* __restrict__ lut,
    const f16* __restrict__ plwh, const f16* __restrict__ plwl,
    const float* __restrict__ plb,
    f16* __restrict__ och_h, f16* __restrict__ och_l) {
  __shared__ f16 KH[BLK][PAD], KL[BLK][PAD], VH[BLK][PAD], PH[BLK][PAD];
  __shared__ float ksq[DD], dinv[BLK];
  int L = blockIdx.x;
  int bh = (L & 7) * 4 + ((L >> 3) & 3);  // xcd-grouped by bh
  int n = L >> 5;
  int id = bh * NQ + n;
  int b = bh >> 2, h = bh & 3;
  int tid = threadIdx.x;
  int w = tid >> 6, lane = tid & 63, c16 = lane & 15, g = lane >> 4;
  int lu[TT];
#pragma unroll
  for (int t = 0; t < TT; ++t) lu[t] = lut[(size_t)id * TT + t];
  // Q fragments direct from global
  size_t qbase = ((size_t)bh * LL + (size_t)n * BLK + w * 16 + c16) * DD;
  half8 bqh[2], bql[2];
#pragma unroll
  for (int ks = 0; ks < 2; ++ks) {
    bqh[ks] = *(const half8*)(qh_g + qbase + ks * 32 + g * 8);
    bql[ks] = *(const half8*)(ql_g + qbase + ks * 32 + g * 8);
  }
  f32x4 acco[4];
#pragma unroll
  for (int j = 0; j < 4; ++j) acco[j] = (f32x4){0.f,0.f,0.f,0.f};
  float m_run = -INFINITY, l_run = 0.f;
  for (int t = 0; t < TT; ++t) {
    int mb = lu[t];
#pragma unroll
    for (int it = 0; it < 2; ++it) {
      int idx = it * 256 + tid; int pos = idx >> 3, dp8 = idx & 7;
      size_t kb2 = ((size_t)bh * LL + (size_t)mb * BLK + pos) * DD + dp8 * 8;
      *(uint4v*)&KH[pos][dp8 * 8] = *(const uint4v*)(kh_g + kb2);
      *(uint4v*)&KL[pos][dp8 * 8] = *(const uint4v*)(kl_g + kb2);
      *(uint4v*)&VH[pos][dp8 * 8] =
          *(const uint4v*)(vT_g + ((size_t)bh * DD + pos) * LL + (size_t)mb * BLK + dp8 * 8);
    }
    __syncthreads();
    float p[4][4];
    float mx = m_run;
#pragma unroll
    for (int i = 0; i < 4; ++i) {
      f32x4 acc = {0.f, 0.f, 0.f, 0.f};
      f32x4 accc = {0.f, 0.f, 0.f, 0.f};
#pragma unroll
      for (int ks = 0; ks < 2; ++ks) {
        half8 ah = *(const half8*)&KH[i * 16 + c16][ks * 32 + g * 8];
        half8 al = *(const half8*)&KL[i * 16 + c16][ks * 32 + g * 8];
        acc  = MFMA16(ah, bqh[ks], acc);
        accc = MFMA16(ah, bql[ks], accc);
        accc = MFMA16(al, bqh[ks], accc);
      }
#pragma unroll
      for (int r = 0; r < 4; ++r) {
        p[i][r] = (acc[r] + accc[r] * INV2048) * 0.125f;
        mx = fmaxf(mx, p[i][r]);
      }
    }
    mx = fmaxf(mx, __shfl_xor(mx, 16));
    mx = fmaxf(mx, __shfl_xor(mx, 32));
    float fac = __expf(m_run - mx);
    float rs = 0.f;
#pragma unroll
    for (int i = 0; i < 4; ++i)
#pragma unroll
      for (int r = 0; r < 4; ++r) { p[i][r] = __expf(p[i][r] - mx); rs += p[i][r]; }
    rs += __shfl_xor(rs, 16);
    rs += __shfl_xor(rs, 32);
    l_run = l_run * fac + rs;
    m_run = mx;
#pragma unroll
    for (int j = 0; j < 4; ++j)
#pragma unroll
      for (int r = 0; r < 4; ++r) acco[j][r] *= fac;
#pragma unroll
    for (int i = 0; i < 4; ++i) {
      H4 pp;
      pp.h[0] = (f16)p[i][0]; pp.h[1] = (f16)p[i][1]; pp.h[2] = (f16)p[i][2]; pp.h[3] = (f16)p[i][3];
      *(ull*)&PH[w * 16 + c16][i * 16 + g * 4] = pp.u;
    }
#pragma unroll
    for (int ks = 0; ks < 2; ++ks) {
      half8 pb = *(const half8*)&PH[w * 16 + c16][ks * 32 + g * 8];
#pragma unroll
      for (int j = 0; j < 4; ++j) {
        half8 vhf = *(const half8*)&VH[j * 16 + c16][ks * 32 + g * 8];
        acco[j] = MFMA16(vhf, pb, acco[j]);
      }
    }
    __syncthreads();
  }
  float linv = 1.f / l_run;
#pragma unroll
  for (int j = 0; j < 4; ++j)
#pragma unroll
    for (int r = 0; r < 4; ++r) acco[j][r] *= linv;
  // ---- linear path ----
  if (tid < DD) {
    float s = kstot[(size_t)bh * DD + tid];
#pragma unroll
    for (int t2 = 0; t2 < TT; ++t2) s -= ksum[((size_t)bh * NKB + lu[t2]) * DD + tid];
    ksq[tid] = s;
  }
  int cr = tid >> 2, cp = tid & 3;
  float cq[16];
  {
    size_t qrow = ((size_t)bh * LL + (size_t)n * BLK + cr) * DD + cp * 16;
    half8 qa = *(const half8*)(qh_g + qrow), qa2 = *(const half8*)(qh_g + qrow + 8);
    half8 qb1 = *(const half8*)(ql_g + qrow), qb2 = *(const half8*)(ql_g + qrow + 8);
#pragma unroll
    for (int c = 0; c < 8; ++c) {
      cq[c] = (float)qa[c] + (float)qb1[c] * INV2048;
      cq[8 + c] = (float)qa2[c] + (float)qb2[c] * INV2048;
    }
    float mx2 = -INFINITY;
#pragma unroll
    for (int c = 0; c < 16; ++c) mx2 = fmaxf(mx2, cq[c]);
    mx2 = fmaxf(mx2, __shfl_xor(mx2, 1));
    mx2 = fmaxf(mx2, __shfl_xor(mx2, 2));
    float sum = 0.f;
#pragma unroll
    for (int c = 0; c < 16; ++c) { cq[c] = __expf(cq[c] - mx2); sum += cq[c]; }
    sum += __shfl_xor(sum, 1);
    sum += __shfl_xor(sum, 2);
    float inv = 1.f / sum;
#pragma unroll
    for (int c = 0; c < 16; ++c) cq[c] *= inv;
  }
#pragma unroll
  for (int c = 0; c < 8; ++c) {
    H2 hh, ll;
    hh.h[0] = (f16)cq[2 * c];     ll.h[0] = (f16)((cq[2 * c] - (float)hh.h[0]) * 2048.f);
    hh.h[1] = (f16)cq[2 * c + 1]; ll.h[1] = (f16)((cq[2 * c + 1] - (float)hh.h[1]) * 2048.f);
    *(unsigned int*)&VH[cr][cp * 16 + 2 * c] = hh.u;
    *(unsigned int*)&PH[cr][cp * 16 + 2 * c] = ll.u;
  }
  {
    const float* kvtp = kvtot + (size_t)bh * DD * DD;
    const float* kvbp = kvb + (size_t)bh * NKB * DD * DD;
    for (int it = 0; it < 16; ++it) {
      int idx = it * 256 + tid;
      int e = idx & 63, dd2 = idx >> 6;
      float s = kvtp[dd2 * DD + e];
#pragma unroll
      for (int t2 = 0; t2 < TT; ++t2) s -= kvbp[(size_t)lu[t2] * DD * DD + dd2 * DD + e];
      f16 sh = (f16)s;
      KH[e][dd2] = sh;
      KL[e][dd2] = (f16)((s - (float)sh) * 2048.f);
    }
  }
  __syncthreads();
  {
    float dpart = 0.f;
#pragma unroll
    for (int c = 0; c < 16; ++c) dpart += cq[c] * ksq[cp * 16 + c];
    dpart += __shfl_xor(dpart, 1);
    dpart += __shfl_xor(dpart, 2);
    if (cp == 0) dinv[cr] = 1.f / (dpart + 1e-6f);
  }
  f32x4 accn[4], accn2[4];
  {
    half8 cqh[2], cql[2];
#pragma unroll
    for (int ks = 0; ks < 2; ++ks) {
      cqh[ks] = *(const half8*)&VH[w * 16 + c16][ks * 32 + g * 8];
      cql[ks] = *(const half8*)&PH[w * 16 + c16][ks * 32 + g * 8];
    }
#pragma unroll
    for (int j = 0; j < 4; ++j) {
      f32x4 acc = {0.f, 0.f, 0.f, 0.f};
      f32x4 accc = {0.f, 0.f, 0.f, 0.f};
#pragma unroll
      for (int ks = 0; ks < 2; ++ks) {
        half8 ah = *(const half8*)&KH[j * 16 + c16][ks * 32 + g * 8];
        half8 al = *(const half8*)&KL[j * 16 + c16][ks * 32 + g * 8];
        acc  = MFMA16(ah, cqh[ks], acc);
        accc = MFMA16(ah, cql[ks], accc);
        accc = MFMA16(al, cqh[ks], accc);
      }
      accn[j] = acc; accn2[j] = accc;
    }
  }
  __syncthreads();
  float di = dinv[w * 16 + c16];
#pragma unroll
  for (int j = 0; j < 4; ++j) {
    float o0 = (accn[j][0] + accn2[j][0] * INV2048) * di;
    float o1 = (accn[j][1] + accn2[j][1] * INV2048) * di;
    float o2 = (accn[j][2] + accn2[j][2] * INV2048) * di;
    float o3 = (accn[j][3] + accn2[j][3] * INV2048) * di;
    H4 hh, ll;
    hh.h[0] = (f16)o0; ll.h[0] = (f16)((o0 - (float)hh.h[0]) * 2048.f);
    hh.h[1] = (f16)o1; ll.h[1] = (f16)((o1 - (float)hh.h[1]) * 2048.f);
    hh.h[2] = (f16)o2; ll.h[2] = (f16)((o2 - (float)hh.h[2]) * 2048.f);
    hh.h[3] = (f16)o3; ll.h[3] = (f16)((o3 - (float)hh.h[3]) * 2048.f);
    *(ull*)&PH[w * 16 + c16][j * 16 + g * 4] = hh.u;
    *(ull*)&KH[w * 16 + c16][j * 16 + g * 4] = ll.u;
  }
  f32x4 accf2[4];
#pragma unroll
  for (int j = 0; j < 4; ++j) accf2[j] = (f32x4){0.f,0.f,0.f,0.f};
#pragma unroll
  for (int ks = 0; ks < 2; ++ks) {
    half8 bolh = *(const half8*)&PH[w * 16 + c16][ks * 32 + g * 8];
    half8 boll = *(const half8*)&KH[w * 16 + c16][ks * 32 + g * 8];
#pragma unroll
    for (int j = 0; j < 4; ++j) {
      size_t pwoff = (size_t)(j * 16 + c16) * DD + ks * 32 + g * 8;
      half8 awh = *(const half8*)(plwh + pwoff);
      half8 awl = *(const half8*)(plwl + pwoff);
      acco[j]  = MFMA16(awh, bolh, acco[j]);
      accf2[j] = MFMA16(awh, boll, accf2[j]);
      accf2[j] = MFMA16(awl, bolh, accf2[j]);
    }
  }
  size_t obase = ((size_t)b * LL + (size_t)n * BLK + w * 16 + c16) * NC + h * DD;
#pragma unroll
  for (int j = 0; j < 4; ++j) {
    H4 hh, ll;
#pragma unroll
    for (int r = 0; r < 4; ++r) {
      int e2 = j * 16 + g * 4 + r;
      float v = acco[j][r] + accf2[j][r] * INV2048 + plb[e2];
      hh.h[r] = (f16)v;
      ll.h[r] = (f16)((v - (float)hh.h[r]) * 2048.f);
    }
    *(ull*)(och_h + obase + j * 16 + g * 4) = hh.u;
    *(ull*)(och_l + obase + j * 16 + g * 4) = ll.u;
  }
}

// ---------------- out projection: A=W_out (global frags), B=och (LDS) -------
__global__ __launch_bounds__(256) void out_mfma(
    const f16* __restrict__ och_h, const f16* __restrict__ och_l,
    const f16* __restrict__ wh, const f16* __restrict__ wl,
    float* __restrict__ out) {
  __shared__ f16 OH[BLK][PAD], OL[BLK][PAD];
  int l0 = blockIdx.x * 64;
  int o0 = blockIdx.y * 64;
  int b = blockIdx.z;
  int tid = threadIdx.x;
  int w = tid >> 6, lane = tid & 63, c16 = lane & 15, g = lane >> 4;
  f32x4 acc[4], acc2[4];
#pragma unroll
  for (int j = 0; j < 4; ++j) { acc[j] = (f32x4){0.f,0.f,0.f,0.f}; acc2[j] = (f32x4){0.f,0.f,0.f,0.f}; }
  size_t wbase = (size_t)(o0 + w * 16 + c16) * NC;
  for (int c0 = 0; c0 < NC; c0 += 64) {
    __syncthreads();
#pragma unroll
    for (int it = 0; it < 2; ++it) {
      int idx = it * 256 + tid; int pos = idx >> 3, dp8 = idx & 7;
      size_t gsrc = ((size_t)b * LL + l0 + pos) * NC + c0 + dp8 * 8;
      *(uint4v*)&OH[pos][dp8 * 8] = *(const uint4v*)(och_h + gsrc);
      *(uint4v*)&OL[pos][dp8 * 8] = *(const uint4v*)(och_l + gsrc);
    }
    __syncthreads();
#pragma unroll
    for (int ks = 0; ks < 2; ++ks) {
      half8 awh = *(const half8*)(wh + wbase + c0 + ks * 32 + g * 8);
      half8 awl = *(const half8*)(wl + wbase + c0 + ks * 32 + g * 8);
#pragma unroll
      for (int j = 0; j < 4; ++j) {
        half8 bh = *(const half8*)&OH[j * 16 + c16][ks * 32 + g * 8];
        half8 bl = *(const half8*)&OL[j * 16 + c16][ks * 32 + g * 8];
        acc[j]  = MFMA16(awh, bh, acc[j]);
        acc2[j] = MFMA16(awh, bl, acc2[j]);
        acc2[j] = MFMA16(awl, bh, acc2[j]);
      }
    }
  }
#pragma unroll
  for (int j = 0; j < 4; ++j)
#pragma unroll
    for (int r = 0; r < 4; ++r)
      out[((size_t)b * NC + o0 + w * 16 + g * 4 + r) * LL + l0 + j * 16 + c16] =
          acc[j][r] + acc2[j][r] * INV2048;
}

extern "C" void kernel_launch(void* const* d_in, const int* in_sizes, int n_in,
                              void* d_out, int out_size, void* d_ws, size_t ws_size,
                              hipStream_t stream) {
  (void)in_sizes; (void)n_in; (void)out_size; (void)ws_size;
  const float* x = (const float*)d_in[0];
  const float* qkv_w = (const float*)d_in[1];
  const float* out_w = (const float*)d_in[2];
  const float* plw = (const float*)d_in[3];
  const float* plb = (const float*)d_in[4];
  float* out = (float*)d_out;
  const size_t E = (size_t)NB * NHH * LL * DD;  // 8388608
  f16* fb = (f16*)d_ws;
  f16* qh = fb;            f16* ql = qh + E;
  f16* kh = ql + E;        f16* kl = kh + E;
  f16* vh = kl + E;        f16* vl = vh + E;
  f16* vT = vl + E;
  f16* xTh = vT + E;       f16* xTl = xTh + E;
  // och aliases xT (xT consumed by qkv_mfma before attn writes och)
  f16* och_h = xTh;        f16* och_l = xTl;
  float* fbase = (float*)(xTl + E);
  float* kvb = fbase;
  float* ksum = kvb + E;
  float* kvtot = ksum + (size_t)NB * NHH * NKB * DD;
  float* kstot = kvtot + (size_t)NB * NHH * DD * DD;
  float* xb = kstot + (size_t)NB * NHH * DD;
  float* qb = xb + (size_t)NB * NC * NQ;
  float* kb = qb + (size_t)NB * NHH * NQ * DD;
  int* lut = (int*)(kb + (size_t)NB * NHH * NQ * DD);
  f16* wqh = (f16*)(lut + (size_t)NB * NHH * NQ * TT);
  f16* wql = wqh + (size_t)3 * NC * NC;
  f16* woh = wql + (size_t)3 * NC * NC;
  f16* wol = woh + (size_t)NC * NC;
  f16* plwh = wol + (size_t)NC * NC;
  f16* plwl = plwh + (size_t)DD * DD;

  xb_kernel<<<NB * NC, 64, 0, stream>>>(x, xb);
  qbkb_kernel<<<NB * NQ * NHH, 128, 0, stream>>>(qkv_w, xb, qb, kb);
  topk_kernel<<<NB * NHH * NQ, 64, 0, stream>>>(qb, kb, lut);
  split_kernel<<<192, 256, 0, stream>>>(qkv_w, wqh, wql, 3 * NC * NC);
  split_kernel<<<64, 256, 0, stream>>>(out_w, woh, wol, NC * NC);
  split_kernel<<<4, 256, 0, stream>>>(plw, plwh, plwl, DD * DD);
  xsplit_kernel<<<dim3(LL / 64, NC / 64, NB), 256, 0, stream>>>(x, xTh, xTl);
  qkv_mfma<<<LL / 64 * 12 * NB, 256, 0, stream>>>(xTh, xTl, wqh, wql, qh, ql, kh, kl, vh, vl);
  vtrans_kernel<<<NB * NHH * NQ, 256, 0, stream>>>(vh, vT);
  kvb_kernel<<<NB * NHH * NKB, 256, 0, stream>>>(kh, kl, vh, vl, kvb, ksum);
  totals_kernel<<<NB * NHH * 16, 256, 0, stream>>>(kvb, ksum, kvtot, kstot);
  attn_mfma<<<NB * NHH * NQ, 256, 0, stream>>>(qh, ql, kh, kl, vT, kvb, ksum, kvtot, kstot,
                                               lut, plwh, plwl, plb, och_h, och_l);
  out_mfma<<<dim3(LL / 64, NC / 64, NB), 256, 0, stream>>>(och_h, och_l, woh, wol, out);
}